// Round 4
// baseline (353.865 us; speedup 1.0000x reference)
//
#include <hip/hip_runtime.h>

typedef __bf16 bf16x8 __attribute__((ext_vector_type(8)));
typedef float f32x4 __attribute__((ext_vector_type(4)));

#define DIM 1024
#define NSEQ 2048

// ---------------- RMSNorm: fp32 in, bf16 out ----------------
__global__ __launch_bounds__(256) void rmsnorm_kernel(const float* __restrict__ x,
                                                      const float* __restrict__ g,
                                                      __bf16* __restrict__ o) {
    int row = blockIdx.x;
    int t = threadIdx.x;
    float4 xv = ((const float4*)(x + (size_t)row * DIM))[t];
    float ss = xv.x*xv.x + xv.y*xv.y + xv.z*xv.z + xv.w*xv.w;
    #pragma unroll
    for (int off = 32; off; off >>= 1) ss += __shfl_xor(ss, off, 64);
    __shared__ float red[4];
    if ((t & 63) == 0) red[t >> 6] = ss;
    __syncthreads();
    ss = red[0] + red[1] + red[2] + red[3];
    float r = rsqrtf(ss * (1.0f / 1024.0f) + 1.1920929e-07f);
    float4 gv = ((const float4*)g)[t];
    union { uint2 u; __bf16 h[4]; } p;
    p.h[0] = (__bf16)(xv.x * r * gv.x);
    p.h[1] = (__bf16)(xv.y * r * gv.y);
    p.h[2] = (__bf16)(xv.z * r * gv.z);
    p.h[3] = (__bf16)(xv.w * r * gv.w);
    *(uint2*)(o + (size_t)row * DIM + t * 4) = p.u;
}

// ---------------- RoPE in-place on (4096 x 1024) bf16, heads of 64 ----------------
__global__ __launch_bounds__(256) void rope_kernel(__bf16* __restrict__ x) {
    int gid = blockIdx.x * 256 + threadIdx.x;   // one pair per thread
    int row = gid >> 9;          // 512 pairs per row
    int pr = gid & 511;
    int pos = row & (NSEQ - 1);
    int dp = pr & 31;            // pair index within head
    float inv = __expf(-(float)dp * (9.210340371976184f / 32.0f)); // 10000^(-2dp/64)
    float ang = (float)pos * inv;
    float sn, cs;
    sincosf(ang, &sn, &cs);
    size_t off = (size_t)row * DIM + pr * 2;
    union { unsigned int u; __bf16 h[2]; } p;
    p.u = *(const unsigned int*)(x + off);
    float x1 = (float)p.h[0], x2 = (float)p.h[1];
    p.h[0] = (__bf16)(x1 * cs - x2 * sn);
    p.h[1] = (__bf16)(x2 * cs + x1 * sn);
    *(unsigned int*)(x + off) = p.u;
}

// ---------------- GEMM: C[i,j] = scale * sum_k A[i,k] * B[j,k] ----------------
// A: 4096x1024 bf16 row-major; B: 1024x1024 row-major (acts as B^T),
// bf16 or fp32 (fp32 converted to bf16 during LDS staging); C: bf16 or fp32.
#define LDT 40   // padded LDS stride (elements); 80B rows, 2-way-free banks
template <typename BT, typename CT>
__global__ __launch_bounds__(256) void gemm_bt_kernel(const __bf16* __restrict__ A,
                                                      const BT* __restrict__ B,
                                                      CT* __restrict__ C,
                                                      float scale) {
    __shared__ __bf16 As[128 * LDT];
    __shared__ __bf16 Bs[128 * LDT];
    int bm = blockIdx.x, bn = blockIdx.y;
    int t = threadIdx.x;
    int w = t >> 6, l = t & 63;
    int wm = (w >> 1) * 64, wn = (w & 1) * 64;   // wave 2x2 grid, each 64x64
    int lrow = l & 15, lq = l >> 4;
    f32x4 acc[4][4] = {};
    for (int kt = 0; kt < 32; ++kt) {
        int k0 = kt * 32;
        // A tile: 128x32 bf16, 512 x 16B
        #pragma unroll
        for (int it = 0; it < 2; ++it) {
            int idx = t + it * 256;
            int row = idx >> 2;
            int c8 = (idx & 3) * 8;
            *(uint4*)&As[row * LDT + c8] =
                *(const uint4*)(A + (size_t)(bm * 128 + row) * DIM + k0 + c8);
        }
        // B tile: 128x32
        if constexpr (sizeof(BT) == 2) {
            #pragma unroll
            for (int it = 0; it < 2; ++it) {
                int idx = t + it * 256;
                int row = idx >> 2;
                int c8 = (idx & 3) * 8;
                *(uint4*)&Bs[row * LDT + c8] =
                    *(const uint4*)((const __bf16*)B + (size_t)(bn * 128 + row) * DIM + k0 + c8);
            }
        } else {
            // fp32 weights: load float4, convert to bf16, store 8B
            #pragma unroll
            for (int it = 0; it < 4; ++it) {
                int idx = t + it * 256;          // 1024 x float4 covers 128x32 fp32
                int row = idx >> 3;
                int c4 = (idx & 7) * 4;
                float4 f = *(const float4*)((const float*)B + (size_t)(bn * 128 + row) * DIM + k0 + c4);
                union { uint2 u; __bf16 h[4]; } pk;
                pk.h[0] = (__bf16)f.x; pk.h[1] = (__bf16)f.y;
                pk.h[2] = (__bf16)f.z; pk.h[3] = (__bf16)f.w;
                *(uint2*)&Bs[row * LDT + c4] = pk.u;
            }
        }
        __syncthreads();
        bf16x8 af[4], bfr[4];
        #pragma unroll
        for (int i = 0; i < 4; ++i)
            af[i] = *(const bf16x8*)&As[(wm + i * 16 + lrow) * LDT + lq * 8];
        #pragma unroll
        for (int i = 0; i < 4; ++i)
            bfr[i] = *(const bf16x8*)&Bs[(wn + i * 16 + lrow) * LDT + lq * 8];
        #pragma unroll
        for (int rt = 0; rt < 4; ++rt)
            #pragma unroll
            for (int ct = 0; ct < 4; ++ct)
                acc[rt][ct] = __builtin_amdgcn_mfma_f32_16x16x32_bf16(
                    af[rt], bfr[ct], acc[rt][ct], 0, 0, 0);
        __syncthreads();
    }
    #pragma unroll
    for (int rt = 0; rt < 4; ++rt)
        #pragma unroll
        for (int ct = 0; ct < 4; ++ct)
            #pragma unroll
            for (int r = 0; r < 4; ++r) {
                int row = bm * 128 + wm + rt * 16 + lq * 4 + r;   // C-layout: row=(l>>4)*4+reg
                int col = bn * 128 + wn + ct * 16 + lrow;          //           col=l&15
                C[(size_t)row * DIM + col] = (CT)(acc[rt][ct][r] * scale);
            }
}

// ---------------- Causal flash attention ----------------
// q,k,v,o: (4096 x 1024) bf16; head h occupies cols [h*64, h*64+64)
// block = one (b, h, 64-row q-tile); 4 waves, each owns 16 q-rows
__global__ __launch_bounds__(256) void attn_kernel(const __bf16* __restrict__ q,
                                                   const __bf16* __restrict__ kk,
                                                   const __bf16* __restrict__ v,
                                                   __bf16* __restrict__ o) {
    int blk = blockIdx.x;
    int qt = blk & 31;
    int h = (blk >> 5) & 15;
    int b = blk >> 9;
    int rowbase = b * NSEQ;
    int t = threadIdx.x;
    int w = t >> 6, l = t & 63;
    int lrow = l & 15, lq = l >> 4;

    __shared__ __bf16 Kt[64 * 72];       // [j][d], stride 72
    __shared__ __bf16 Vt[64 * 72];       // TRANSPOSED: [d][j], stride 72
    __shared__ __bf16 Ps[4 * 16 * 72];   // per-wave P strip, C-layout -> A-layout bounce
    __bf16* pw = &Ps[w * 16 * 72];

    // Q fragment (A-layout): m = l&15 -> q-row, k = (l>>4)*8+j
    const __bf16* qp = q + (size_t)(rowbase + qt * 64 + w * 16 + lrow) * DIM + h * 64;
    bf16x8 qa0 = *(const bf16x8*)(qp + lq * 8);
    bf16x8 qa1 = *(const bf16x8*)(qp + 32 + lq * 8);

    f32x4 oacc[4] = {};
    float m_r[4], l_r[4];
    #pragma unroll
    for (int r = 0; r < 4; ++r) { m_r[r] = -1e30f; l_r[r] = 0.0f; }

    for (int jt = 0; jt <= qt; ++jt) {
        // stage K tile row-major (vectorized 16B)
        #pragma unroll
        for (int it = 0; it < 2; ++it) {
            int idx = t + it * 256;
            int row = idx >> 3;
            int c8 = (idx & 7) * 8;
            *(uint4*)&Kt[row * 72 + c8] =
                *(const uint4*)(kk + (size_t)(rowbase + jt * 64 + row) * DIM + h * 64 + c8);
        }
        // stage V tile transposed (coalesced global read, scattered LDS write)
        {
            int row = t >> 2;
            int d0 = (t & 3) * 16;
            const __bf16* vp = v + (size_t)(rowbase + jt * 64 + row) * DIM + h * 64 + d0;
            bf16x8 v0 = *(const bf16x8*)vp;
            bf16x8 v1 = *(const bf16x8*)(vp + 8);
            #pragma unroll
            for (int e = 0; e < 8; ++e) Vt[(d0 + e) * 72 + row] = v0[e];
            #pragma unroll
            for (int e = 0; e < 8; ++e) Vt[(d0 + 8 + e) * 72 + row] = v1[e];
        }
        __syncthreads();

        // S strip (16 q-rows x 64 keys): B-op lane holds K[n=l&15][k=(l>>4)*8+j]
        f32x4 s[4];
        #pragma unroll
        for (int ct = 0; ct < 4; ++ct) {
            f32x4 z = {};
            bf16x8 kb0 = *(const bf16x8*)&Kt[(ct * 16 + lrow) * 72 + lq * 8];
            bf16x8 kb1 = *(const bf16x8*)&Kt[(ct * 16 + lrow) * 72 + 32 + lq * 8];
            z = __builtin_amdgcn_mfma_f32_16x16x32_bf16(qa0, kb0, z, 0, 0, 0);
            z = __builtin_amdgcn_mfma_f32_16x16x32_bf16(qa1, kb1, z, 0, 0, 0);
            s[ct] = z;
        }
        // causal mask on diagonal tile
        if (jt == qt) {
            #pragma unroll
            for (int ct = 0; ct < 4; ++ct)
                #pragma unroll
                for (int r = 0; r < 4; ++r) {
                    int col = ct * 16 + lrow;
                    int rw = w * 16 + lq * 4 + r;
                    if (col > rw) s[ct][r] = -3.0e38f;
                }
        }
        // online softmax; row (l>>4)*4+r replicated across a 16-lane group -> xor 1..8
        float alpha[4];
        #pragma unroll
        for (int r = 0; r < 4; ++r) {
            float mx = fmaxf(fmaxf(s[0][r], s[1][r]), fmaxf(s[2][r], s[3][r]));
            #pragma unroll
            for (int off = 8; off; off >>= 1) mx = fmaxf(mx, __shfl_xor(mx, off, 64));
            float mnew = fmaxf(m_r[r], mx);
            alpha[r] = __expf(m_r[r] - mnew);
            float ps = 0.0f;
            #pragma unroll
            for (int ct = 0; ct < 4; ++ct) {
                float p = __expf(s[ct][r] - mnew);
                s[ct][r] = p;
                ps += p;
            }
            #pragma unroll
            for (int off = 8; off; off >>= 1) ps += __shfl_xor(ps, off, 64);
            l_r[r] = l_r[r] * alpha[r] + ps;
            m_r[r] = mnew;
        }
        // P: C-layout -> LDS -> A-layout (per-wave private region, no barrier needed)
        #pragma unroll
        for (int ct = 0; ct < 4; ++ct)
            #pragma unroll
            for (int r = 0; r < 4; ++r)
                pw[(lq * 4 + r) * 72 + ct * 16 + lrow] = (__bf16)s[ct][r];
        // rescale O by alpha (same lane->row grouping as S)
        #pragma unroll
        for (int ct = 0; ct < 4; ++ct) {
            oacc[ct][0] *= alpha[0]; oacc[ct][1] *= alpha[1];
            oacc[ct][2] *= alpha[2]; oacc[ct][3] *= alpha[3];
        }
        // O += P @ V : A = P[m=i][k=j], B = V[k=j][n=d] read from transposed Vt
        #pragma unroll
        for (int ch = 0; ch < 2; ++ch) {
            bf16x8 pa = *(const bf16x8*)&pw[lrow * 72 + ch * 32 + lq * 8];
            #pragma unroll
            for (int ct = 0; ct < 4; ++ct) {
                bf16x8 vb = *(const bf16x8*)&Vt[(ct * 16 + lrow) * 72 + ch * 32 + lq * 8];
                oacc[ct] = __builtin_amdgcn_mfma_f32_16x16x32_bf16(pa, vb, oacc[ct], 0, 0, 0);
            }
        }
        __syncthreads();
    }
    // epilogue: O /= l, write bf16
    #pragma unroll
    for (int ct = 0; ct < 4; ++ct)
        #pragma unroll
        for (int r = 0; r < 4; ++r) {
            int row = qt * 64 + w * 16 + lq * 4 + r;
            int col = ct * 16 + lrow;
            float val = oacc[ct][r] / l_r[r];
            o[(size_t)(rowbase + row) * DIM + h * 64 + col] = (__bf16)val;
        }
}

extern "C" void kernel_launch(void* const* d_in, const int* in_sizes, int n_in,
                              void* d_out, int out_size, void* d_ws, size_t ws_size,
                              hipStream_t stream) {
    // Per the harness contract: fp32 reference => fp32 inputs AND fp32 output.
    const float* tokens = (const float*)d_in[0];
    const float* gamma  = (const float*)d_in[1];
    const float* wq = (const float*)d_in[2];
    const float* wk = (const float*)d_in[3];
    const float* wv = (const float*)d_in[4];
    const float* wo = (const float*)d_in[5];

    __bf16* ws  = (__bf16*)d_ws;
    __bf16* x   = ws;                           // 4096*1024 (dead after QKV GEMMs)
    __bf16* qb  = x   + (size_t)4096 * 1024;
    __bf16* kb  = qb  + (size_t)4096 * 1024;
    __bf16* vb  = kb  + (size_t)4096 * 1024;
    __bf16* ao  = x;                            // alias: attn out reuses x's buffer
    float*  out = (float*)d_out;                // fp32 output buffer

    rmsnorm_kernel<<<4096, 256, 0, stream>>>(tokens, gamma, x);

    dim3 gg(32, 8);
    gemm_bt_kernel<float, __bf16><<<gg, 256, 0, stream>>>(x, wq, qb, 0.125f); // q * Dh^-0.5
    gemm_bt_kernel<float, __bf16><<<gg, 256, 0, stream>>>(x, wk, kb, 1.0f);
    gemm_bt_kernel<float, __bf16><<<gg, 256, 0, stream>>>(x, wv, vb, 1.0f);

    rope_kernel<<<8192, 256, 0, stream>>>(qb);
    rope_kernel<<<8192, 256, 0, stream>>>(kb);

    attn_kernel<<<1024, 256, 0, stream>>>(qb, kb, vb, ao);                    // 2*16*32 blocks

    gemm_bt_kernel<float, float><<<gg, 256, 0, stream>>>(ao, wo, out, 1.0f);  // fp32 store
}